// Round 9
// baseline (100.371 us; speedup 1.0000x reference)
//
#include <hip/hip_runtime.h>
#include <math.h>

#define NBOX 98            // 7*7*2
#define ROWLEN 1470        // floats per image
#define NMS_T 0.7f
#define SCORE_T 0.05f

// precise sigmoid — bit-matches the reference path (rare IoU-boundary recompute only)
__device__ __forceinline__ float psigm(float v) {
    return 1.0f / (1.0f + expf(-v));
}
// fast sigmoid: native exp + v_rcp_f32; box coords only (0.38 output tolerance)
__device__ __forceinline__ float fsigm(float v) {
    return __builtin_amdgcn_rcpf(1.0f + __expf(-v));
}

// One wave per image, lane = cell, NO LDS: each lane loads its cell's 30
// contiguous floats straight from global (base 8B-aligned: img*5880 + cell*120).
// Loads pipeline into uses — no vmcnt(0) full-drain barrier, no ds_read chain.
//
// Structural fact (any input): after decode+clamp, every box except the two
// anchors of cell (0,0) is degenerate (x1==x2==1 for cj>=1, y1==y2==1 for
// ci>=1) -> IoU==0 with everything -> greedy NMS reduces to one IoU check
// (box0 vs box1 of cell 0). Sort = stable rank by (score desc, index asc) via
// packed 64-bit key + fully-unrolled readlane loop.
__global__ __launch_bounds__(256) void yolo_post(const float* __restrict__ x,
                                                 float* __restrict__ out,
                                                 int batch) {
    const int wid  = threadIdx.x >> 6;
    const int lane = threadIdx.x & 63;
    const int img  = blockIdx.x * 4 + wid;      // 4 independent waves per block
    if (img >= batch) return;

    const int  cell   = lane;
    const bool active = (cell < 49);

    // per-cell pointer; inactive lanes clamp to cell 0 (harmless reads, in-bounds)
    const float* c = x + (size_t)img * ROWLEN + (active ? cell : 0) * 30;

    // ---- load 30 floats: float2 @0, then 7x float4 @ {2,6,10,14,18,22,26} ----
    const float2 d0  = *reinterpret_cast<const float2*>(c);        // c[0..1]
    const float4 d1  = *reinterpret_cast<const float4*>(c + 2);    // c[2..5]
    const float4 d2  = *reinterpret_cast<const float4*>(c + 6);    // c[6..9]
    const float4 q0  = *reinterpret_cast<const float4*>(c + 10);   // classes 0..3
    const float4 q1  = *reinterpret_cast<const float4*>(c + 14);   // 4..7
    const float4 q2  = *reinterpret_cast<const float4*>(c + 18);   // 8..11
    const float4 q3  = *reinterpret_cast<const float4*>(c + 22);   // 12..15
    const float4 q4  = *reinterpret_cast<const float4*>(c + 26);   // 16..19

    // ---- class argmax (first occurrence) ----
    float cls[20] = {q0.x,q0.y,q0.z,q0.w, q1.x,q1.y,q1.z,q1.w,
                     q2.x,q2.y,q2.z,q2.w, q3.x,q3.y,q3.z,q3.w,
                     q4.x,q4.y,q4.z,q4.w};
    float mx = cls[0]; int ml = 0;
    #pragma unroll
    for (int t = 1; t < 20; ++t) {
        if (cls[t] > mx) { mx = cls[t]; ml = t; }
    }
    const float s   = active ? mx : 0.0f;
    const float lab = (float)ml;

    // ---- decode boxes ----
    int vbits = 0;
    float4 B0 = make_float4(1.f, 1.f, 1.f, 1.f);
    float4 B1 = make_float4(1.f, 1.f, 1.f, 1.f);
    if (active) {
        const int ci = cell / 7;
        const int cj = cell - ci * 7;
        if (d1.z >= 0.0f) vbits |= 1;            // c[4]: sigmoid(o)>=0.5 <=> o>=0
        if (d2.w >= 0.0f) vbits |= 2;            // c[9]

        const float sx0 = fsigm(d0.x), sy0 = fsigm(d0.y);   // c[0],c[1]
        const float sw0 = fsigm(d1.x), sh0 = fsigm(d1.y);   // c[2],c[3]
        const float sx1 = fsigm(d1.w), sy1 = fsigm(d2.x);   // c[5],c[6]
        const float sw1 = fsigm(d2.y), sh1 = fsigm(d2.z);   // c[7],c[8]

        if (cj == 0) {                           // else exact 1.0 from clamp
            B0.x = fminf(fmaxf(sx0, 0.f), 1.f);
            B0.z = fminf(fmaxf(sx0 + sw0, 0.f), 1.f);
            B1.x = fminf(fmaxf(sx1, 0.f), 1.f);
            B1.z = fminf(fmaxf(sx1 + sw1, 0.f), 1.f);
        }
        if (ci == 0) {
            B0.y = fminf(fmaxf(sy0, 0.f), 1.f);
            B0.w = fminf(fmaxf(sy0 + sh0, 0.f), 1.f);
            B1.y = fminf(fmaxf(sy1, 0.f), 1.f);
            B1.w = fminf(fmaxf(sy1 + sh1, 0.f), 1.f);
        }
    }

    const bool v0 = (vbits & 1) != 0;
    const bool v1 = (vbits & 2) != 0;
    const int  cnt = (vbits & 1) + (vbits >> 1);

    const unsigned long long V0m = __ballot(v0);
    const unsigned long long V1m = __ballot(v1);
    const int V = (int)__popcll(V0m) + (int)__popcll(V1m);

    // ---- the single possible suppression: box1 by box0 (cell 0) ----
    bool kill_local = false;
    if (cell == 0 && (vbits & 3) == 3) {
        const float a0 = (B0.z - B0.x) * (B0.w - B0.y);
        const float a1 = (B1.z - B1.x) * (B1.w - B1.y);
        const float w  = fmaxf(fminf(B0.z, B1.z) - fmaxf(B0.x, B1.x), 0.f);
        const float h  = fmaxf(fminf(B0.w, B1.w) - fmaxf(B0.y, B1.y), 0.f);
        const float inter = w * h;
        const float uni   = a0 + a1 - inter;
        const float delta = inter - NMS_T * uni;
        if (fabsf(delta) < 1e-4f * uni) {
            // fast-sigmoid error could flip the decision -> ref-exact recompute
            const float px0 = psigm(d0.x), py0 = psigm(d0.y);
            const float pw0 = psigm(d1.x), ph0 = psigm(d1.y);
            const float px1 = psigm(d1.w), py1 = psigm(d2.x);
            const float pw1 = psigm(d2.y), ph1 = psigm(d2.z);
            const float X0 = fminf(fmaxf(px0, 0.f), 1.f), Y0 = fminf(fmaxf(py0, 0.f), 1.f);
            const float Z0 = fminf(fmaxf(px0 + pw0, 0.f), 1.f), W0 = fminf(fmaxf(py0 + ph0, 0.f), 1.f);
            const float X1 = fminf(fmaxf(px1, 0.f), 1.f), Y1 = fminf(fmaxf(py1, 0.f), 1.f);
            const float Z1 = fminf(fmaxf(px1 + pw1, 0.f), 1.f), W1 = fminf(fmaxf(py1 + ph1, 0.f), 1.f);
            const float pa0 = (Z0 - X0) * (W0 - Y0);
            const float pa1 = (Z1 - X1) * (W1 - Y1);
            const float pw  = fmaxf(fminf(Z0, Z1) - fmaxf(X0, X1), 0.f);
            const float ph  = fmaxf(fminf(W0, W1) - fmaxf(Y0, Y1), 0.f);
            const float pint = pw * ph;
            const float puni = pa0 + pa1 - pint;
            const float iou  = (puni > 0.f) ? (pint / puni) : 0.f;
            kill_local = (iou > NMS_T);
        } else {
            kill_local = (delta > 0.f);
        }
    }
    const bool kill1 = (__ballot(kill_local) != 0ull);

    // ---- packed key: (ord(score)<<8) | (63-cell)<<2 | cnt — score desc, cell asc ----
    const int ib = __float_as_int(s);
    const unsigned uo = (unsigned)ib ^ (unsigned)((ib >> 31) | 0x80000000);
    const unsigned long long key =
        ((unsigned long long)uo << 8) | ((unsigned)(63 - cell) << 2) | (unsigned)cnt;
    const unsigned klo = (unsigned)key;
    const unsigned khi = (unsigned)(key >> 32);

    int acc0 = 0, acc1 = 0, acc2 = 0, acc3 = 0;
    #pragma unroll
    for (int j = 0; j < 49; ++j) {
        const unsigned jlo = (unsigned)__builtin_amdgcn_readlane((int)klo, j);
        const unsigned jhi = (unsigned)__builtin_amdgcn_readlane((int)khi, j);
        const unsigned long long kj = ((unsigned long long)jhi << 32) | jlo;
        const int cj_ = (int)(jlo & 3u);
        const int add = (kj > key) ? cj_ : 0;
        if ((j & 3) == 0) acc0 += add;
        else if ((j & 3) == 1) acc1 += add;
        else if ((j & 3) == 2) acc2 += add;
        else acc3 += add;
    }
    const int rcom = (acc0 + acc1) + (acc2 + acc3);

    const unsigned long long below = (1ull << cell) - 1ull;
    const int prefv = (int)__popcll(V0m & below) + (int)__popcll(V1m & below);

    const int r0 = v0 ? rcom : (V + 2 * cell - prefv);
    const int r1 = v1 ? (rcom + (v0 ? 1 : 0))
                      : (V + 2 * cell + 1 - prefv - (v0 ? 1 : 0));

    const bool k0 = v0 && (s >= SCORE_T);
    const bool k1 = v1 && (s >= SCORE_T) && !(kill1 && cell == 0);

    // ---- scatter outputs: boxes [b,98,4] | scores | labels | keep ----
    if (active) {
        float4* boxes = reinterpret_cast<float4*>(out + (size_t)img * (NBOX * 4));
        const size_t base1 = (size_t)batch * (NBOX * 4);
        const size_t bn    = (size_t)batch * NBOX;
        float* scores = out + base1 +          (size_t)img * NBOX;
        float* labels = out + base1 + bn +     (size_t)img * NBOX;
        float* keepm  = out + base1 + 2 * bn + (size_t)img * NBOX;

        const float4 z = make_float4(0.f, 0.f, 0.f, 0.f);
        boxes[r0]  = k0 ? B0 : z;
        boxes[r1]  = k1 ? B1 : z;
        scores[r0] = k0 ? s : 0.f;
        scores[r1] = k1 ? s : 0.f;
        labels[r0] = k0 ? lab : 0.f;
        labels[r1] = k1 ? lab : 0.f;
        keepm[r0]  = k0 ? 1.f : 0.f;
        keepm[r1]  = k1 ? 1.f : 0.f;
    }
}

extern "C" void kernel_launch(void* const* d_in, const int* in_sizes, int n_in,
                              void* d_out, int out_size, void* d_ws, size_t ws_size,
                              hipStream_t stream) {
    const float* x = (const float*)d_in[0];
    float* out = (float*)d_out;
    const int batch = in_sizes[0] / ROWLEN;   // 8192
    const int grid  = (batch + 3) / 4;        // 4 adjacent images per block, 1 per wave
    yolo_post<<<grid, 256, 0, stream>>>(x, out, batch);
}

// Round 10
// 100.016 us; speedup vs baseline: 1.0035x; 1.0035x over previous
//
#include <hip/hip_runtime.h>
#include <math.h>

#define NBOX 98            // 7*7*2
#define ROWLEN 1470        // floats per image
#define NMS_T 0.7f
#define SCORE_T 0.05f

// precise sigmoid — bit-matches the reference path (rare IoU-boundary recompute only)
__device__ __forceinline__ float psigm(float v) {
    return 1.0f / (1.0f + expf(-v));
}
// fast sigmoid: native exp + v_rcp_f32; box coords only (0.38 output tolerance)
__device__ __forceinline__ float fsigm(float v) {
    return __builtin_amdgcn_rcpf(1.0f + __expf(-v));
}

// one cell's 30 floats, register-resident
struct CellData {
    float2 d0;                       // c[0..1]
    float4 d1, d2;                   // c[2..5], c[6..9]
    float4 q0, q1, q2, q3, q4;       // 20 class logits
};

__device__ __forceinline__ CellData load_cell(const float* __restrict__ c) {
    CellData r;
    r.d0 = *reinterpret_cast<const float2*>(c);
    r.d1 = *reinterpret_cast<const float4*>(c + 2);
    r.d2 = *reinterpret_cast<const float4*>(c + 6);
    r.q0 = *reinterpret_cast<const float4*>(c + 10);
    r.q1 = *reinterpret_cast<const float4*>(c + 14);
    r.q2 = *reinterpret_cast<const float4*>(c + 18);
    r.q3 = *reinterpret_cast<const float4*>(c + 22);
    r.q4 = *reinterpret_cast<const float4*>(c + 26);
    return r;
}

// left-biased argmax tree node: keeps first occurrence on ties
__device__ __forceinline__ void amx(float av, int ai, float bv, int bi,
                                    float& ov, int& oi) {
    const bool l = (av >= bv);
    ov = l ? av : bv;
    oi = l ? ai : bi;
}

// Full per-image pipeline from registers. Structural fact (any input): after
// decode+clamp, every box except the two anchors of cell (0,0) is degenerate
// (x1==x2==1 for cj>=1, y1==y2==1 for ci>=1) -> IoU==0 with everything ->
// greedy NMS reduces to one IoU check (box0 vs box1 of cell 0). Sort = stable
// rank by (score desc, index asc) via packed 64-bit key + readlane loop.
__device__ __forceinline__ void process(const CellData& D, int img, int lane,
                                        float* __restrict__ out, int batch) {
    const int  cell   = lane;
    const bool active = (cell < 49);

    // ---- class argmax, depth-5 left-biased tree (first occurrence on tie) ----
    float cls[20] = {D.q0.x,D.q0.y,D.q0.z,D.q0.w, D.q1.x,D.q1.y,D.q1.z,D.q1.w,
                     D.q2.x,D.q2.y,D.q2.z,D.q2.w, D.q3.x,D.q3.y,D.q3.z,D.q3.w,
                     D.q4.x,D.q4.y,D.q4.z,D.q4.w};
    float pv[10]; int pi[10];
    #pragma unroll
    for (int t = 0; t < 10; ++t) amx(cls[2*t], 2*t, cls[2*t+1], 2*t+1, pv[t], pi[t]);
    float rv[5]; int ri[5];
    #pragma unroll
    for (int t = 0; t < 5; ++t) amx(pv[2*t], pi[2*t], pv[2*t+1], pi[2*t+1], rv[t], ri[t]);
    float u0v, u1v; int u0i, u1i;
    amx(rv[0], ri[0], rv[1], ri[1], u0v, u0i);
    amx(rv[2], ri[2], rv[3], ri[3], u1v, u1i);
    float wv; int wi;
    amx(u0v, u0i, u1v, u1i, wv, wi);
    float mx; int ml;
    amx(wv, wi, rv[4], ri[4], mx, ml);

    const float s   = active ? mx : 0.0f;
    const float lab = (float)ml;

    // ---- decode boxes ----
    int vbits = 0;
    float4 B0 = make_float4(1.f, 1.f, 1.f, 1.f);
    float4 B1 = make_float4(1.f, 1.f, 1.f, 1.f);
    if (active) {
        const int ci = cell / 7;
        const int cj = cell - ci * 7;
        if (D.d1.z >= 0.0f) vbits |= 1;          // c[4]: sigmoid(o)>=0.5 <=> o>=0
        if (D.d2.w >= 0.0f) vbits |= 2;          // c[9]

        const float sx0 = fsigm(D.d0.x), sy0 = fsigm(D.d0.y);   // c[0],c[1]
        const float sw0 = fsigm(D.d1.x), sh0 = fsigm(D.d1.y);   // c[2],c[3]
        const float sx1 = fsigm(D.d1.w), sy1 = fsigm(D.d2.x);   // c[5],c[6]
        const float sw1 = fsigm(D.d2.y), sh1 = fsigm(D.d2.z);   // c[7],c[8]

        if (cj == 0) {                           // else exact 1.0 from clamp
            B0.x = fminf(fmaxf(sx0, 0.f), 1.f);
            B0.z = fminf(fmaxf(sx0 + sw0, 0.f), 1.f);
            B1.x = fminf(fmaxf(sx1, 0.f), 1.f);
            B1.z = fminf(fmaxf(sx1 + sw1, 0.f), 1.f);
        }
        if (ci == 0) {
            B0.y = fminf(fmaxf(sy0, 0.f), 1.f);
            B0.w = fminf(fmaxf(sy0 + sh0, 0.f), 1.f);
            B1.y = fminf(fmaxf(sy1, 0.f), 1.f);
            B1.w = fminf(fmaxf(sy1 + sh1, 0.f), 1.f);
        }
    }

    const bool v0 = (vbits & 1) != 0;
    const bool v1 = (vbits & 2) != 0;
    const int  cnt = (vbits & 1) + (vbits >> 1);

    const unsigned long long V0m = __ballot(v0);
    const unsigned long long V1m = __ballot(v1);
    const int V = (int)__popcll(V0m) + (int)__popcll(V1m);

    // ---- the single possible suppression: box1 by box0 (cell 0) ----
    bool kill_local = false;
    if (cell == 0 && (vbits & 3) == 3) {
        const float a0 = (B0.z - B0.x) * (B0.w - B0.y);
        const float a1 = (B1.z - B1.x) * (B1.w - B1.y);
        const float w  = fmaxf(fminf(B0.z, B1.z) - fmaxf(B0.x, B1.x), 0.f);
        const float h  = fmaxf(fminf(B0.w, B1.w) - fmaxf(B0.y, B1.y), 0.f);
        const float inter = w * h;
        const float uni   = a0 + a1 - inter;
        const float delta = inter - NMS_T * uni;
        if (fabsf(delta) < 1e-4f * uni) {
            // fast-sigmoid error could flip the decision -> ref-exact recompute
            const float px0 = psigm(D.d0.x), py0 = psigm(D.d0.y);
            const float pw0 = psigm(D.d1.x), ph0 = psigm(D.d1.y);
            const float px1 = psigm(D.d1.w), py1 = psigm(D.d2.x);
            const float pw1 = psigm(D.d2.y), ph1 = psigm(D.d2.z);
            const float X0 = fminf(fmaxf(px0, 0.f), 1.f), Y0 = fminf(fmaxf(py0, 0.f), 1.f);
            const float Z0 = fminf(fmaxf(px0 + pw0, 0.f), 1.f), W0 = fminf(fmaxf(py0 + ph0, 0.f), 1.f);
            const float X1 = fminf(fmaxf(px1, 0.f), 1.f), Y1 = fminf(fmaxf(py1, 0.f), 1.f);
            const float Z1 = fminf(fmaxf(px1 + pw1, 0.f), 1.f), W1 = fminf(fmaxf(py1 + ph1, 0.f), 1.f);
            const float pa0 = (Z0 - X0) * (W0 - Y0);
            const float pa1 = (Z1 - X1) * (W1 - Y1);
            const float pw  = fmaxf(fminf(Z0, Z1) - fmaxf(X0, X1), 0.f);
            const float ph  = fmaxf(fminf(W0, W1) - fmaxf(Y0, Y1), 0.f);
            const float pint = pw * ph;
            const float puni = pa0 + pa1 - pint;
            const float iou  = (puni > 0.f) ? (pint / puni) : 0.f;
            kill_local = (iou > NMS_T);
        } else {
            kill_local = (delta > 0.f);
        }
    }
    const bool kill1 = (__ballot(kill_local) != 0ull);

    // ---- packed key: (ord(score)<<8) | (63-cell)<<2 | cnt — score desc, cell asc ----
    const int ib = __float_as_int(s);
    const unsigned uo = (unsigned)ib ^ (unsigned)((ib >> 31) | 0x80000000);
    const unsigned long long key =
        ((unsigned long long)uo << 8) | ((unsigned)(63 - cell) << 2) | (unsigned)cnt;
    const unsigned klo = (unsigned)key;
    const unsigned khi = (unsigned)(key >> 32);

    int acc0 = 0, acc1 = 0, acc2 = 0, acc3 = 0;
    #pragma unroll
    for (int j = 0; j < 49; ++j) {
        const unsigned jlo = (unsigned)__builtin_amdgcn_readlane((int)klo, j);
        const unsigned jhi = (unsigned)__builtin_amdgcn_readlane((int)khi, j);
        const unsigned long long kj = ((unsigned long long)jhi << 32) | jlo;
        const int cj_ = (int)(jlo & 3u);
        const int add = (kj > key) ? cj_ : 0;
        if ((j & 3) == 0) acc0 += add;
        else if ((j & 3) == 1) acc1 += add;
        else if ((j & 3) == 2) acc2 += add;
        else acc3 += add;
    }
    const int rcom = (acc0 + acc1) + (acc2 + acc3);

    const unsigned long long below = (1ull << cell) - 1ull;
    const int prefv = (int)__popcll(V0m & below) + (int)__popcll(V1m & below);

    const int r0 = v0 ? rcom : (V + 2 * cell - prefv);
    const int r1 = v1 ? (rcom + (v0 ? 1 : 0))
                      : (V + 2 * cell + 1 - prefv - (v0 ? 1 : 0));

    const bool k0 = v0 && (s >= SCORE_T);
    const bool k1 = v1 && (s >= SCORE_T) && !(kill1 && cell == 0);

    // ---- scatter outputs: boxes [b,98,4] | scores | labels | keep ----
    if (active) {
        float4* boxes = reinterpret_cast<float4*>(out + (size_t)img * (NBOX * 4));
        const size_t base1 = (size_t)batch * (NBOX * 4);
        const size_t bn    = (size_t)batch * NBOX;
        float* scores = out + base1 +          (size_t)img * NBOX;
        float* labels = out + base1 + bn +     (size_t)img * NBOX;
        float* keepm  = out + base1 + 2 * bn + (size_t)img * NBOX;

        const float4 z = make_float4(0.f, 0.f, 0.f, 0.f);
        boxes[r0]  = k0 ? B0 : z;
        boxes[r1]  = k1 ? B1 : z;
        scores[r0] = k0 ? s : 0.f;
        scores[r1] = k1 ? s : 0.f;
        labels[r0] = k0 ? lab : 0.f;
        labels[r1] = k1 ? lab : 0.f;
        keepm[r0]  = k0 ? 1.f : 0.f;
        keepm[r1]  = k1 ? 1.f : 0.f;
    }
}

// Each wave owns TWO adjacent images, fully register-resident (no LDS, no
// barriers). All 16 loads (both images) issue upfront; image B's loads age to
// completion during image A's ~1700-cycle compute, so B's first-use wait is
// free — one cold-miss stall amortized over two images. Waves in a block are
// fully independent.
__global__ __launch_bounds__(256) void yolo_post(const float* __restrict__ x,
                                                 float* __restrict__ out,
                                                 int batch) {
    const int wid  = threadIdx.x >> 6;
    const int lane = threadIdx.x & 63;
    const int gw   = blockIdx.x * 4 + wid;      // wave id
    const int imgA = 2 * gw;
    const int imgB = 2 * gw + 1;
    if (imgA >= batch) return;                  // wave-uniform

    const int cellOff = (lane < 49 ? lane : 0) * 30;   // inactive lanes clamp to cell 0
    const float* cA = x + (size_t)imgA * ROWLEN + cellOff;

    const bool hasB = (imgB < batch);           // wave-uniform
    const float* cB = hasB ? (x + (size_t)imgB * ROWLEN + cellOff) : cA;

    // issue ALL loads before any compute
    const CellData A = load_cell(cA);
    const CellData B = load_cell(cB);

    process(A, imgA, lane, out, batch);
    if (hasB) process(B, imgB, lane, out, batch);
}

extern "C" void kernel_launch(void* const* d_in, const int* in_sizes, int n_in,
                              void* d_out, int out_size, void* d_ws, size_t ws_size,
                              hipStream_t stream) {
    const float* x = (const float*)d_in[0];
    float* out = (float*)d_out;
    const int batch = in_sizes[0] / ROWLEN;     // 8192
    const int waves = (batch + 1) / 2;          // 2 adjacent images per wave
    const int grid  = (waves + 3) / 4;          // 4 waves per 256-thread block
    yolo_post<<<grid, 256, 0, stream>>>(x, out, batch);
}